// Round 5
// baseline (132.091 us; speedup 1.0000x reference)
//
#include <hip/hip_runtime.h>
#include <math.h>

typedef __attribute__((ext_vector_type(8))) short bf16x8;
typedef __attribute__((ext_vector_type(16))) float fx16;

#define SEQ 2048
#define HD 64

// ---------- helpers ----------
__device__ __forceinline__ unsigned f2bf_bits(float f){
  unsigned u = __float_as_uint(f);
  return (u + 0x7fffu + ((u >> 16) & 1u)) >> 16;   // RNE to bf16
}
__device__ __forceinline__ unsigned cvt_pk_bf16(float a, float b){
  unsigned r;
  asm("v_cvt_pk_bf16_f32 %0, %1, %2" : "=v"(r) : "v"(a), "v"(b));
  return r;  // [15:0]=bf16(a), [31:16]=bf16(b)
}
__device__ __forceinline__ float lo16f(unsigned u){ return __uint_as_float(u << 16); }
__device__ __forceinline__ float hi16f(unsigned u){ return __uint_as_float(u & 0xffff0000u); }
union U8 { bf16x8 v; short s[8]; unsigned u[4]; };

__device__ __forceinline__ fx16 mfma_bf16(bf16x8 a, bf16x8 b, fx16 c){
  return __builtin_amdgcn_mfma_f32_32x32x16_bf16(a, b, c, 0, 0, 0);
}
__device__ __forceinline__ fx16 fzero(){
  fx16 z;
#pragma unroll
  for (int i = 0; i < 16; ++i) z[i] = 0.f;
  return z;
}

// ---------- W -> MFMA B-fragment layout ----------
// group gid = (stage*6 + t)*2 + half, stage 0..63 (k=16 each), t = n-tile 0..5.
// Lane (l31,h): col n=t*32+l31, k = stage*16 + h*8 + i.
__global__ __launch_bounds__(256) void wconv_kernel(
    const float* __restrict__ Wq, const float* __restrict__ Wk, const float* __restrict__ Wv,
    short* __restrict__ wsB)
{
  int gid = blockIdx.x * 4 + (threadIdx.x >> 6);  // 0..767
  int lane = threadIdx.x & 63;
  int l31 = lane & 31, h = lane >> 5;
  int half = gid & 1;
  int rem = gid >> 1;            // stage*6 + t
  int t = rem % 6;
  int stage = rem / 6;           // 0..63
  int n = t * 32 + l31;
  int mat = n >> 6, col = n & 63;
  const float* W = (mat == 0) ? Wq : (mat == 1) ? Wk : Wv;
  int kbase = stage * 16 + h * 8;
  U8 o;
#pragma unroll
  for (int i = 0; i < 8; ++i) {
    float f = W[(size_t)(kbase + i) * 64 + col];
    unsigned hb = f2bf_bits(f);
    if (half == 0) o.s[i] = (short)hb;
    else {
      float hf = __uint_as_float(hb << 16);
      o.s[i] = (short)f2bf_bits(f - hf);
    }
  }
  *(bf16x8*)(wsB + (size_t)gid * 512 + lane * 8) = o.v;
}

// ---------- QKV projection: m97-style. 64 rows x 192 cols, BK=64 ----------
// 256 thr (4 waves): mw = w&1 (rows mw*32), nset = (w>>1)*3 (3 n-tiles).
// x staged fp32 via global_load_lds (double-buffered, 16B-XOR swizzle).
// W B-frags read direct from L2 (wsB). One barrier per K-step.
__global__ __launch_bounds__(256) void proj_kernel(
    const float* __restrict__ x, const short* __restrict__ wsB,
    short* __restrict__ qh, short* __restrict__ ql,
    short* __restrict__ kh, short* __restrict__ kl,
    short* __restrict__ vth, short* __restrict__ vtl)
{
  __shared__ float Xs[2][4096];   // [buf][64 rows x 64 k], byte layout row*256 + chunk*16, swizzled
  __shared__ float Vb[64 * 68];   // v transpose bounce (epilogue)

  const int tid = threadIdx.x;
  const int lane = tid & 63, w = tid >> 6;
  const int l31 = lane & 31, h = lane >> 5;
  const int mw = w & 1;
  const int nset = (w >> 1) * 3;
  const int row0 = blockIdx.x * 64;

  // staging geometry: issue i covers rows i*16 + (tid>>4); chunk = tid&15, source-swizzled
  const int stg_row = tid >> 4;
  const int stg_c = (tid & 15) ^ (stg_row & 7);
  const size_t stg_off = (size_t)stg_row * 1024 + stg_c * 4;

  fx16 accP[3], accQ[3];
#pragma unroll
  for (int t = 0; t < 3; ++t) { accP[t] = fzero(); accQ[t] = fzero(); }

  // prologue stage
  {
    const float* gs = x + (size_t)row0 * 1024 + 0 * 64 + stg_off;
    char* lb = (char*)&Xs[0][0];
#pragma unroll
    for (int i = 0; i < 4; ++i)
      __builtin_amdgcn_global_load_lds(
        (const __attribute__((address_space(1))) float*)(gs + (size_t)i * 16 * 1024),
        (__attribute__((address_space(3))) float*)(lb + i * 4096 + tid * 16), 16, 0, 0);
  }
  __syncthreads();

  const int arow = mw * 32 + l31;
  const int rsw = arow & 7;

  for (int step = 0; step < 16; ++step) {
    const int p = step & 1;
    if (step < 15) {
      const float* gs = x + (size_t)row0 * 1024 + (step + 1) * 64 + stg_off;
      char* lb = (char*)&Xs[p ^ 1][0];
#pragma unroll
      for (int i = 0; i < 4; ++i)
        __builtin_amdgcn_global_load_lds(
          (const __attribute__((address_space(1))) float*)(gs + (size_t)i * 16 * 1024),
          (__attribute__((address_space(3))) float*)(lb + i * 4096 + tid * 16), 16, 0, 0);
    }
    const char* xb = (const char*)&Xs[p][0] + arow * 256;
#pragma unroll
    for (int ks = 0; ks < 4; ++ks) {
      float4 fa = *(const float4*)(xb + (((ks * 4 + h * 2)     ^ rsw) * 16));
      float4 fb = *(const float4*)(xb + (((ks * 4 + h * 2 + 1) ^ rsw) * 16));
      U8 ah, al;
      ah.u[0] = cvt_pk_bf16(fa.x, fa.y);
      ah.u[1] = cvt_pk_bf16(fa.z, fa.w);
      ah.u[2] = cvt_pk_bf16(fb.x, fb.y);
      ah.u[3] = cvt_pk_bf16(fb.z, fb.w);
      al.u[0] = cvt_pk_bf16(fa.x - lo16f(ah.u[0]), fa.y - hi16f(ah.u[0]));
      al.u[1] = cvt_pk_bf16(fa.z - lo16f(ah.u[1]), fa.w - hi16f(ah.u[1]));
      al.u[2] = cvt_pk_bf16(fb.x - lo16f(ah.u[2]), fb.y - hi16f(ah.u[2]));
      al.u[3] = cvt_pk_bf16(fb.z - lo16f(ah.u[3]), fb.w - hi16f(ah.u[3]));
      const int sidx = step * 4 + ks;
#pragma unroll
      for (int tt = 0; tt < 3; ++tt) {
        const size_t g2 = ((size_t)sidx * 6 + nset + tt) * 2;
        bf16x8 Bh = *(const bf16x8*)(wsB + g2 * 512 + lane * 8);
        bf16x8 Bl = *(const bf16x8*)(wsB + g2 * 512 + 512 + lane * 8);
        accP[tt] = mfma_bf16(ah.v, Bh, accP[tt]);
        accQ[tt] = mfma_bf16(ah.v, Bl, accQ[tt]);
        accQ[tt] = mfma_bf16(al.v, Bh, accQ[tt]);
      }
    }
    __syncthreads();
  }

  // epilogue: q,k direct hi/lo stores; v via LDS transpose bounce (verified R2)
#pragma unroll
  for (int t = 0; t < 3; ++t) {
    int nt = nset + t;
    int mat = nt >> 1;
    int colb = (nt & 1) * 32 + l31;
    if (mat < 2) {
      short* dh = (mat == 0) ? qh : kh;
      short* dl = (mat == 0) ? ql : kl;
#pragma unroll
      for (int r = 0; r < 16; ++r) {
        float f = accP[t][r] + accQ[t][r];
        int rowg = row0 + mw * 32 + (r & 3) + 8 * (r >> 2) + 4 * h;
        unsigned hb = f2bf_bits(f);
        float hf = __uint_as_float(hb << 16);
        unsigned lb = f2bf_bits(f - hf);
        dh[(size_t)rowg * 64 + colb] = (short)hb;
        dl[(size_t)rowg * 64 + colb] = (short)lb;
      }
    } else {
#pragma unroll
      for (int r = 0; r < 16; ++r) {
        float f = accP[t][r] + accQ[t][r];
        int srel = mw * 32 + (r & 3) + 8 * (r >> 2) + 4 * h;
        Vb[srel * 68 + (nt - 4) * 32 + l31] = f;
      }
    }
  }
  __syncthreads();
  {
    int d = tid >> 2, sc = (tid & 3) * 16;
    int bb = row0 >> 11, s0 = row0 & 2047;
    U8 hv0, hv1, lv0, lv1;
#pragma unroll
    for (int ss = 0; ss < 16; ++ss) {
      float f = Vb[(sc + ss) * 68 + d];
      unsigned hb = f2bf_bits(f);
      float hf = __uint_as_float(hb << 16);
      unsigned lb = f2bf_bits(f - hf);
      if (ss < 8) { hv0.s[ss] = (short)hb; lv0.s[ss] = (short)lb; }
      else        { hv1.s[ss - 8] = (short)hb; lv1.s[ss - 8] = (short)lb; }
    }
    size_t o = (size_t)(bb * 64 + d) * 2048 + s0 + sc;
    *(bf16x8*)(vth + o) = hv0.v;  *(bf16x8*)(vth + o + 8) = hv1.v;
    *(bf16x8*)(vtl + o) = lv0.v;  *(bf16x8*)(vtl + o + 8) = lv1.v;
  }
}

// ---------- Flash attention: 1 wave = 32 q-cols, K-step 32, no LDS, no barriers ----------
// Causal split-k: q-tile qt has nseg = (qt>>3)+1 segments of <=8 K-steps.
// grid = 2304 = 8 batches x 288 (bid = r*8 + b for XCD pinning).
__global__ __launch_bounds__(64) void attn_kernel(
    const short* __restrict__ qh, const short* __restrict__ ql,
    const short* __restrict__ kh, const short* __restrict__ kl,
    const short* __restrict__ vth, const short* __restrict__ vtl,
    float* __restrict__ segO, float* __restrict__ segL, float* __restrict__ segM)
{
  const int bid = blockIdx.x;
  const int b = bid & 7;
  const int r = bid >> 3;               // 0..287
  int g = 0;
  while (r >= 4 * (g + 1) * (g + 2)) ++g;   // g = 0..7
  const int rr = r - 4 * g * (g + 1);
  const int qt = g * 8 + rr / (g + 1);
  const int sg = rr % (g + 1);
  const int nk = qt + 1;                // total 32-k steps for this q-tile
  const int nsg = g + 1;
  const int bs = nk / nsg, rem = nk % nsg;
  const int nsteps = bs + (sg < rem ? 1 : 0);
  const int kt0 = sg * bs + (sg < rem ? sg : rem);

  const int lane = threadIdx.x;
  const int l31 = lane & 31, h = lane >> 5;
  const int qabs = qt * 32 + l31;

  // Q B-frags (hoisted): B[kk=d][col=q]
  bf16x8 qf0[4], qf1[4];
  {
    size_t qrow = ((size_t)b * 2048 + qabs) * 64;
#pragma unroll
    for (int ds = 0; ds < 4; ++ds) {
      qf0[ds] = *(const bf16x8*)(qh + qrow + ds * 16 + 8 * h);
      qf1[ds] = *(const bf16x8*)(ql + qrow + ds * 16 + 8 * h);
    }
  }

  fx16 accA0 = fzero(), accA1 = fzero(), accB0 = fzero(), accB1 = fzero();
  float Mrun = -3e38f, lrun = 0.f;

  for (int it = 0; it < nsteps; ++it) {
    const int kt = kt0 + it;
    // K A-frags direct from global (L2): row = kt*32 + l31
    const size_t koff = ((size_t)b * 2048 + (size_t)kt * 32 + l31) * 64 + 8 * h;
    bf16x8 kah[4], kal[4];
#pragma unroll
    for (int ds = 0; ds < 4; ++ds) {
      kah[ds] = *(const bf16x8*)(kh + koff + ds * 16);
      kal[ds] = *(const bf16x8*)(kl + koff + ds * 16);
    }
    fx16 stA = fzero(), stB = fzero();
    __builtin_amdgcn_s_setprio(1);
#pragma unroll
    for (int ds = 0; ds < 4; ++ds) {
      stA = mfma_bf16(kah[ds], qf0[ds], stA);
      stB = mfma_bf16(kah[ds], qf1[ds], stB);
      stB = mfma_bf16(kal[ds], qf0[ds], stB);
    }
    __builtin_amdgcn_s_setprio(0);

    // V A-frags for this step: issue loads early (hide under softmax VALU)
    bf16x8 vfh[2][2], vfl[2][2];
#pragma unroll
    for (int kp = 0; kp < 2; ++kp)
#pragma unroll
      for (int md = 0; md < 2; ++md) {
        const size_t vrow = (size_t)(b * 64 + md * 32 + l31) * 2048 + kt * 32 + kp * 16 + 8 * h;
        vfh[kp][md] = *(const bf16x8*)(vth + vrow);
        vfl[kp][md] = *(const bf16x8*)(vtl + vrow);
      }

    float sv[16];
    const bool diag = (kt == qt);
#pragma unroll
    for (int rr2 = 0; rr2 < 16; ++rr2) {
      float s = (stA[rr2] + stB[rr2]) * 0.125f;
      if (diag) {
        int ka = kt * 32 + (rr2 & 3) + 8 * (rr2 >> 2) + 4 * h;
        if (ka > qabs) s = -3e38f;
      }
      sv[rr2] = s;
    }
    float tm = sv[0];
#pragma unroll
    for (int rr2 = 1; rr2 < 16; ++rr2) tm = fmaxf(tm, sv[rr2]);
    tm = fmaxf(tm, __shfl_xor(tm, 32, 64));
    float Mnew = fmaxf(Mrun, tm);
    float alpha = __expf(Mrun - Mnew);
    Mrun = Mnew;
    float pvv[16]; float psum = 0.f;
#pragma unroll
    for (int rr2 = 0; rr2 < 16; ++rr2) { pvv[rr2] = __expf(sv[rr2] - Mnew); psum += pvv[rr2]; }
    psum += __shfl_xor(psum, 32, 64);
    lrun = lrun * alpha + psum;
#pragma unroll
    for (int rr2 = 0; rr2 < 16; ++rr2) {
      accA0[rr2] *= alpha; accA1[rr2] *= alpha; accB0[rr2] *= alpha; accB1[rr2] *= alpha;
    }
    // P -> bf16 hi/lo packed dwords
    unsigned chv[8], clv[8];
#pragma unroll
    for (int q2 = 0; q2 < 8; ++q2) {
      unsigned c = cvt_pk_bf16(pvv[2 * q2], pvv[2 * q2 + 1]);
      chv[q2] = c;
      clv[q2] = cvt_pk_bf16(pvv[2 * q2] - lo16f(c), pvv[2 * q2 + 1] - hi16f(c));
    }
    // PV: O^T += V^T P^T
#pragma unroll
    for (int kp = 0; kp < 2; ++kp) {
      U8 ph, pl;
      {
        unsigned c0 = chv[4 * kp], c1 = chv[4 * kp + 1], c2 = chv[4 * kp + 2], c3 = chv[4 * kp + 3];
        unsigned x0 = (unsigned)__shfl_xor((int)c0, 32, 64);
        unsigned x1 = (unsigned)__shfl_xor((int)c1, 32, 64);
        unsigned x2 = (unsigned)__shfl_xor((int)c2, 32, 64);
        unsigned x3 = (unsigned)__shfl_xor((int)c3, 32, 64);
        ph.u[0] = h ? x2 : c0;  ph.u[1] = h ? x3 : c1;
        ph.u[2] = h ? c2 : x0;  ph.u[3] = h ? c3 : x1;
        c0 = clv[4 * kp]; c1 = clv[4 * kp + 1]; c2 = clv[4 * kp + 2]; c3 = clv[4 * kp + 3];
        x0 = (unsigned)__shfl_xor((int)c0, 32, 64);
        x1 = (unsigned)__shfl_xor((int)c1, 32, 64);
        x2 = (unsigned)__shfl_xor((int)c2, 32, 64);
        x3 = (unsigned)__shfl_xor((int)c3, 32, 64);
        pl.u[0] = h ? x2 : c0;  pl.u[1] = h ? x3 : c1;
        pl.u[2] = h ? c2 : x0;  pl.u[3] = h ? c3 : x1;
      }
      __builtin_amdgcn_s_setprio(1);
      accA0 = mfma_bf16(vfh[kp][0], ph.v, accA0);
      accB0 = mfma_bf16(vfh[kp][0], pl.v, accB0);
      accB0 = mfma_bf16(vfl[kp][0], ph.v, accB0);
      accA1 = mfma_bf16(vfh[kp][1], ph.v, accA1);
      accB1 = mfma_bf16(vfh[kp][1], pl.v, accB1);
      accB1 = mfma_bf16(vfl[kp][1], ph.v, accB1);
      __builtin_amdgcn_s_setprio(0);
    }
  }

  // write seg partials: O^T [64 d][32 q] + l,m per q
  float* o = segO + (size_t)bid * 2048;
#pragma unroll
  for (int md = 0; md < 2; ++md) {
#pragma unroll
    for (int rr2 = 0; rr2 < 16; ++rr2) {
      int d = md * 32 + (rr2 & 3) + 8 * (rr2 >> 2) + 4 * h;
      float val = md ? (accA1[rr2] + accB1[rr2]) : (accA0[rr2] + accB0[rr2]);
      o[d * 32 + l31] = val;
    }
  }
  if (h == 0) {
    segL[(size_t)bid * 32 + l31] = lrun;
    segM[(size_t)bid * 32 + l31] = Mrun;
  }
}

// ---------- combine: merge <=8 segs per (b, qt), normalize, transpose, write ----------
__global__ __launch_bounds__(256) void combine_kernel(
    const float* __restrict__ segO, const float* __restrict__ segL,
    const float* __restrict__ segM, float* __restrict__ out)
{
  __shared__ float Sc[8][32];
  __shared__ float Linv[32];
  __shared__ float Ot[64 * 40];

  const int bq = blockIdx.x;            // 0..511
  const int b = bq >> 6, qt = bq & 63;
  const int g = qt >> 3, nsg = g + 1;
  const int base = 4 * g * (g + 1) + (qt & 7) * nsg;   // r of seg 0
  const int tid = threadIdx.x;

  if (tid < 32) {
    float M = -3e38f;
    for (int s = 0; s < nsg; ++s)
      M = fmaxf(M, segM[(size_t)((base + s) * 8 + b) * 32 + tid]);
    float L = 0.f;
    for (int s = 0; s < nsg; ++s) {
      float e = __expf(segM[(size_t)((base + s) * 8 + b) * 32 + tid] - M);
      Sc[s][tid] = e;
      L += e * segL[(size_t)((base + s) * 8 + b) * 32 + tid];
    }
    Linv[tid] = 1.f / L;
  }
  __syncthreads();
  {
#pragma unroll
    for (int i = tid; i < 512; i += 256) {
      int d = i >> 3, q4 = (i & 7) * 4;
      float4 acc = {0.f, 0.f, 0.f, 0.f};
      for (int s = 0; s < nsg; ++s) {
        float4 v = *(const float4*)(segO + (size_t)((base + s) * 8 + b) * 2048 + d * 32 + q4);
        acc.x += Sc[s][q4 + 0] * v.x;
        acc.y += Sc[s][q4 + 1] * v.y;
        acc.z += Sc[s][q4 + 2] * v.z;
        acc.w += Sc[s][q4 + 3] * v.w;
      }
      *(float4*)&Ot[d * 40 + q4] = acc;
    }
  }
  __syncthreads();
  {
    const int q = tid >> 3, dc = (tid & 7) * 8;
    const float inv = Linv[q];
    float* dst = out + ((size_t)b * 2048 + qt * 32 + q) * 64 + dc;
#pragma unroll
    for (int i = 0; i < 2; ++i) {
      float4 o;
      o.x = Ot[(dc + 4 * i + 0) * 40 + q] * inv;
      o.y = Ot[(dc + 4 * i + 1) * 40 + q] * inv;
      o.z = Ot[(dc + 4 * i + 2) * 40 + q] * inv;
      o.w = Ot[(dc + 4 * i + 3) * 40 + q] * inv;
      *(float4*)(dst + 4 * i) = o;
    }
  }
}

// ---------- launch ----------
extern "C" void kernel_launch(void* const* d_in, const int* in_sizes, int n_in,
                              void* d_out, int out_size, void* d_ws, size_t ws_size,
                              hipStream_t stream) {
  const float* x  = (const float*)d_in[0];
  const float* Wq = (const float*)d_in[1];
  const float* Wk = (const float*)d_in[2];
  const float* Wv = (const float*)d_in[3];

  char* wsb = (char*)d_ws;
  short* wsB = (short*)(wsb + 0);                     // 786432 B
  short* qh  = (short*)(wsb + 786432);
  short* ql  = (short*)(wsb + 2883584);
  short* kh  = (short*)(wsb + 4980736);
  short* kl  = (short*)(wsb + 7077888);
  short* vth = (short*)(wsb + 9175040);
  short* vtl = (short*)(wsb + 11272192);
  float* segO = (float*)(wsb + 13369344);             // 2304*2048*4 = 18874368 B
  float* segL = (float*)(wsb + 32243712);             // 2304*32*4 = 294912 B
  float* segM = (float*)(wsb + 32538624);             // 294912 B

  wconv_kernel<<<192, 256, 0, stream>>>(Wq, Wk, Wv, wsB);
  proj_kernel<<<256, 256, 0, stream>>>(x, wsB, qh, ql, kh, kl, vth, vtl);
  attn_kernel<<<2304, 64, 0, stream>>>(qh, ql, kh, kl, vth, vtl, segO, segL, segM);
  combine_kernel<<<512, 256, 0, stream>>>(segO, segL, segM, (float*)d_out);
}

// Round 6
// 97.788 us; speedup vs baseline: 1.3508x; 1.3508x over previous
//
#include <hip/hip_runtime.h>
#include <math.h>

typedef __attribute__((ext_vector_type(8))) short bf16x8;
typedef __attribute__((ext_vector_type(16))) float fx16;

#define SEQ 2048
#define HD 64

// ---------- helpers ----------
__device__ __forceinline__ unsigned f2bf_bits(float f){
  unsigned u = __float_as_uint(f);
  return (u + 0x7fffu + ((u >> 16) & 1u)) >> 16;   // RNE to bf16
}
__device__ __forceinline__ unsigned cvt_pk_bf16(float a, float b){
  unsigned r;
  asm("v_cvt_pk_bf16_f32 %0, %1, %2" : "=v"(r) : "v"(a), "v"(b));
  return r;  // [15:0]=bf16(a), [31:16]=bf16(b)
}
__device__ __forceinline__ float lo16f(unsigned u){ return __uint_as_float(u << 16); }
__device__ __forceinline__ float hi16f(unsigned u){ return __uint_as_float(u & 0xffff0000u); }
union U8 { bf16x8 v; short s[8]; unsigned u[4]; };

__device__ __forceinline__ fx16 mfma_bf16(bf16x8 a, bf16x8 b, fx16 c){
  return __builtin_amdgcn_mfma_f32_32x32x16_bf16(a, b, c, 0, 0, 0);
}
__device__ __forceinline__ fx16 fzero(){
  fx16 z;
#pragma unroll
  for (int i = 0; i < 16; ++i) z[i] = 0.f;
  return z;
}

// ---------- W -> MFMA B-fragment layout ----------
// group gid = (stage*6 + t)*2 + half, stage 0..63 (k=16 each), t = n-tile 0..5.
// Lane (l31,h): col n=t*32+l31, k = stage*16 + h*8 + i.
__global__ __launch_bounds__(256) void wconv_kernel(
    const float* __restrict__ Wq, const float* __restrict__ Wk, const float* __restrict__ Wv,
    short* __restrict__ wsB)
{
  int gid = blockIdx.x * 4 + (threadIdx.x >> 6);  // 0..767
  int lane = threadIdx.x & 63;
  int l31 = lane & 31, h = lane >> 5;
  int half = gid & 1;
  int rem = gid >> 1;            // stage*6 + t
  int t = rem % 6;
  int stage = rem / 6;           // 0..63
  int n = t * 32 + l31;
  int mat = n >> 6, col = n & 63;
  const float* W = (mat == 0) ? Wq : (mat == 1) ? Wk : Wv;
  int kbase = stage * 16 + h * 8;
  U8 o;
#pragma unroll
  for (int i = 0; i < 8; ++i) {
    float f = W[(size_t)(kbase + i) * 64 + col];
    unsigned hb = f2bf_bits(f);
    if (half == 0) o.s[i] = (short)hb;
    else {
      float hf = __uint_as_float(hb << 16);
      o.s[i] = (short)f2bf_bits(f - hf);
    }
  }
  *(bf16x8*)(wsB + (size_t)gid * 512 + lane * 8) = o.v;
}

// ---------- QKV projection: BM=32, grid 512 (2 blocks/CU) ----------
// 256 thr (4 waves): nsel = w&1 (3 n-tiles), ksel = w>>1 (K half of 512).
// X direct from global, W B-frags direct from L2, cross-k LDS reduce.
__global__ __launch_bounds__(256) void proj_kernel(
    const float* __restrict__ x, const short* __restrict__ wsB,
    short* __restrict__ qh, short* __restrict__ ql,
    short* __restrict__ kh, short* __restrict__ kl,
    short* __restrict__ vth, short* __restrict__ vtl)
{
  __shared__ float Rx[6 * 16 * 64];   // [tile][r][lane] k-reduce exchange (24KB)
  __shared__ float Vb[32 * 68];       // v transpose bounce (8.7KB)

  const int tid = threadIdx.x;
  const int lane = tid & 63, w = tid >> 6;
  const int l31 = lane & 31, h = lane >> 5;
  const int nsel = w & 1;
  const int ksel = w >> 1;
  const int row0 = blockIdx.x * 32;
  const size_t xbase = (size_t)(row0 + l31) * 1024;

  fx16 acc[3];
#pragma unroll
  for (int t = 0; t < 3; ++t) acc[t] = fzero();

#pragma unroll 4
  for (int s = 0; s < 32; ++s) {
    const int stage = ksel * 32 + s;
    const int k = stage * 16 + h * 8;
    float4 fa = *(const float4*)(x + xbase + k);
    float4 fb = *(const float4*)(x + xbase + k + 4);
    U8 ah, al;
    ah.u[0] = cvt_pk_bf16(fa.x, fa.y);
    ah.u[1] = cvt_pk_bf16(fa.z, fa.w);
    ah.u[2] = cvt_pk_bf16(fb.x, fb.y);
    ah.u[3] = cvt_pk_bf16(fb.z, fb.w);
    al.u[0] = cvt_pk_bf16(fa.x - lo16f(ah.u[0]), fa.y - hi16f(ah.u[0]));
    al.u[1] = cvt_pk_bf16(fa.z - lo16f(ah.u[1]), fa.w - hi16f(ah.u[1]));
    al.u[2] = cvt_pk_bf16(fb.x - lo16f(ah.u[2]), fb.y - hi16f(ah.u[2]));
    al.u[3] = cvt_pk_bf16(fb.z - lo16f(ah.u[3]), fb.w - hi16f(ah.u[3]));
#pragma unroll
    for (int tt = 0; tt < 3; ++tt) {
      const int tg = nsel * 3 + tt;
      const size_t g2 = ((size_t)stage * 6 + tg) * 2;
      bf16x8 Bh = *(const bf16x8*)(wsB + g2 * 512 + lane * 8);
      bf16x8 Bl = *(const bf16x8*)(wsB + g2 * 512 + 512 + lane * 8);
      acc[tt] = mfma_bf16(al.v, Bh, acc[tt]);
      acc[tt] = mfma_bf16(ah.v, Bl, acc[tt]);
      acc[tt] = mfma_bf16(ah.v, Bh, acc[tt]);
    }
  }

  // cross-k reduction: ksel=1 writes, ksel=0 adds
  if (ksel == 1) {
#pragma unroll
    for (int t = 0; t < 3; ++t) {
      const int tg = nsel * 3 + t;
#pragma unroll
      for (int r = 0; r < 16; ++r)
        Rx[tg * 1024 + r * 64 + lane] = acc[t][r];
    }
  }
  __syncthreads();
  if (ksel == 0) {
#pragma unroll
    for (int t = 0; t < 3; ++t) {
      const int tg = nsel * 3 + t;
      const int mat = tg >> 1;
      const int colb = (tg & 1) * 32 + l31;
      if (mat < 2) {
        short* dh = (mat == 0) ? qh : kh;
        short* dl = (mat == 0) ? ql : kl;
#pragma unroll
        for (int r = 0; r < 16; ++r) {
          float f = acc[t][r] + Rx[tg * 1024 + r * 64 + lane];
          int rowg = row0 + (r & 3) + 8 * (r >> 2) + 4 * h;
          unsigned hb = f2bf_bits(f);
          float hf = __uint_as_float(hb << 16);
          unsigned lb = f2bf_bits(f - hf);
          dh[(size_t)rowg * 64 + colb] = (short)hb;
          dl[(size_t)rowg * 64 + colb] = (short)lb;
        }
      } else {
#pragma unroll
        for (int r = 0; r < 16; ++r) {
          float f = acc[t][r] + Rx[tg * 1024 + r * 64 + lane];
          int srel = (r & 3) + 8 * (r >> 2) + 4 * h;
          Vb[srel * 68 + (tg - 4) * 32 + l31] = f;
        }
      }
    }
  }
  __syncthreads();
  {
    int d = tid >> 2, s8 = (tid & 3) * 8;
    int bb = row0 >> 11, s0 = row0 & 2047;
    U8 hv, lv;
#pragma unroll
    for (int ss = 0; ss < 8; ++ss) {
      float f = Vb[(s8 + ss) * 68 + d];
      unsigned hb = f2bf_bits(f);
      float hf = __uint_as_float(hb << 16);
      hv.s[ss] = (short)hb;
      lv.s[ss] = (short)f2bf_bits(f - hf);
    }
    size_t o = (size_t)(bb * 64 + d) * 2048 + s0 + s8;
    *(bf16x8*)(vth + o) = hv.v;
    *(bf16x8*)(vtl + o) = lv.v;
  }
}

// ---------- Flash attention: 1 wave = 32 q-cols, K-step 32, no LDS/barriers ----------
// K-frags prefetched one step ahead; V-frags issued at step top (used post-softmax).
// grid = 2304 = 8 batches x 288 seg-chunks (bid = r*8 + b for XCD spread).
__global__ __launch_bounds__(64) void attn_kernel(
    const short* __restrict__ qh, const short* __restrict__ ql,
    const short* __restrict__ kh, const short* __restrict__ kl,
    const short* __restrict__ vth, const short* __restrict__ vtl,
    float* __restrict__ segO, float* __restrict__ segL, float* __restrict__ segM)
{
  const int bid = blockIdx.x;
  const int b = bid & 7;
  const int r = bid >> 3;               // 0..287
  int g = 0;
  while (r >= 4 * (g + 1) * (g + 2)) ++g;   // g = 0..7
  const int rr = r - 4 * g * (g + 1);
  const int qt = g * 8 + rr / (g + 1);
  const int sg = rr % (g + 1);
  const int nk = qt + 1;
  const int nsg = g + 1;
  const int bs = nk / nsg, rem = nk % nsg;
  const int nsteps = bs + (sg < rem ? 1 : 0);
  const int kt0 = sg * bs + (sg < rem ? sg : rem);

  const int lane = threadIdx.x;
  const int l31 = lane & 31, h = lane >> 5;
  const int qabs = qt * 32 + l31;

  // Q B-frags (hoisted)
  bf16x8 qf0[4], qf1[4];
  {
    size_t qrow = ((size_t)b * 2048 + qabs) * 64;
#pragma unroll
    for (int ds = 0; ds < 4; ++ds) {
      qf0[ds] = *(const bf16x8*)(qh + qrow + ds * 16 + 8 * h);
      qf1[ds] = *(const bf16x8*)(ql + qrow + ds * 16 + 8 * h);
    }
  }

  fx16 acc0 = fzero(), acc1 = fzero();
  float Mrun = -3e38f, lrun = 0.f;

  // prologue: K-frags for kt0
  bf16x8 kah[4], kal[4];
  {
    const size_t koff = ((size_t)b * 2048 + (size_t)kt0 * 32 + l31) * 64 + 8 * h;
#pragma unroll
    for (int ds = 0; ds < 4; ++ds) {
      kah[ds] = *(const bf16x8*)(kh + koff + ds * 16);
      kal[ds] = *(const bf16x8*)(kl + koff + ds * 16);
    }
  }

  for (int it = 0; it < nsteps; ++it) {
    const int kt = kt0 + it;
    // V A-frags for this step: issue first (consumed only after softmax)
    bf16x8 vfh[2][2], vfl[2][2];
#pragma unroll
    for (int kp = 0; kp < 2; ++kp)
#pragma unroll
      for (int md = 0; md < 2; ++md) {
        const size_t vrow = (size_t)(b * 64 + md * 32 + l31) * 2048 + kt * 32 + kp * 16 + 8 * h;
        vfh[kp][md] = *(const bf16x8*)(vth + vrow);
        vfl[kp][md] = *(const bf16x8*)(vtl + vrow);
      }
    // K prefetch for next step (clamped re-read on last iter)
    const int kn = (it + 1 < nsteps) ? kt + 1 : kt;
    bf16x8 knh[4], knl[4];
    {
      const size_t koff = ((size_t)b * 2048 + (size_t)kn * 32 + l31) * 64 + 8 * h;
#pragma unroll
      for (int ds = 0; ds < 4; ++ds) {
        knh[ds] = *(const bf16x8*)(kh + koff + ds * 16);
        knl[ds] = *(const bf16x8*)(kl + koff + ds * 16);
      }
    }

    // QK^T (swapped): S^T = K Q^T, kcur resident in regs
    fx16 stA = fzero(), stB = fzero();
    __builtin_amdgcn_s_setprio(1);
#pragma unroll
    for (int ds = 0; ds < 4; ++ds) {
      stA = mfma_bf16(kah[ds], qf0[ds], stA);
      stB = mfma_bf16(kal[ds], qf0[ds], stB);
      stB = mfma_bf16(kah[ds], qf1[ds], stB);
    }
    __builtin_amdgcn_s_setprio(0);

    float sv[16];
    const bool diag = (kt == qt);
#pragma unroll
    for (int r2 = 0; r2 < 16; ++r2) {
      float s = (stA[r2] + stB[r2]) * 0.125f;
      if (diag) {
        int ka = kt * 32 + (r2 & 3) + 8 * (r2 >> 2) + 4 * h;
        if (ka > qabs) s = -3e38f;
      }
      sv[r2] = s;
    }
    float tm = sv[0];
#pragma unroll
    for (int r2 = 1; r2 < 16; ++r2) tm = fmaxf(tm, sv[r2]);
    tm = fmaxf(tm, __shfl_xor(tm, 32, 64));
    float Mnew = fmaxf(Mrun, tm);
    float alpha = __expf(Mrun - Mnew);
    Mrun = Mnew;
    float psum = 0.f;
#pragma unroll
    for (int r2 = 0; r2 < 16; ++r2) { sv[r2] = __expf(sv[r2] - Mnew); psum += sv[r2]; }
    psum += __shfl_xor(psum, 32, 64);
    lrun = lrun * alpha + psum;
#pragma unroll
    for (int r2 = 0; r2 < 16; ++r2) { acc0[r2] *= alpha; acc1[r2] *= alpha; }

    // P -> bf16 hi/lo packed dwords
    unsigned chv[8], clv[8];
#pragma unroll
    for (int q2 = 0; q2 < 8; ++q2) {
      unsigned c = cvt_pk_bf16(sv[2 * q2], sv[2 * q2 + 1]);
      chv[q2] = c;
      clv[q2] = cvt_pk_bf16(sv[2 * q2] - lo16f(c), sv[2 * q2 + 1] - hi16f(c));
    }
    // PV: O^T += V^T P^T (merged hi/lo accumulators)
#pragma unroll
    for (int kp = 0; kp < 2; ++kp) {
      U8 ph, pl;
      {
        unsigned c0 = chv[4 * kp], c1 = chv[4 * kp + 1], c2 = chv[4 * kp + 2], c3 = chv[4 * kp + 3];
        unsigned x0 = (unsigned)__shfl_xor((int)c0, 32, 64);
        unsigned x1 = (unsigned)__shfl_xor((int)c1, 32, 64);
        unsigned x2 = (unsigned)__shfl_xor((int)c2, 32, 64);
        unsigned x3 = (unsigned)__shfl_xor((int)c3, 32, 64);
        ph.u[0] = h ? x2 : c0;  ph.u[1] = h ? x3 : c1;
        ph.u[2] = h ? c2 : x0;  ph.u[3] = h ? c3 : x1;
        c0 = clv[4 * kp]; c1 = clv[4 * kp + 1]; c2 = clv[4 * kp + 2]; c3 = clv[4 * kp + 3];
        x0 = (unsigned)__shfl_xor((int)c0, 32, 64);
        x1 = (unsigned)__shfl_xor((int)c1, 32, 64);
        x2 = (unsigned)__shfl_xor((int)c2, 32, 64);
        x3 = (unsigned)__shfl_xor((int)c3, 32, 64);
        pl.u[0] = h ? x2 : c0;  pl.u[1] = h ? x3 : c1;
        pl.u[2] = h ? c2 : x0;  pl.u[3] = h ? c3 : x1;
      }
      __builtin_amdgcn_s_setprio(1);
      acc0 = mfma_bf16(vfl[kp][0], ph.v, acc0);
      acc0 = mfma_bf16(vfh[kp][0], pl.v, acc0);
      acc0 = mfma_bf16(vfh[kp][0], ph.v, acc0);
      acc1 = mfma_bf16(vfl[kp][1], ph.v, acc1);
      acc1 = mfma_bf16(vfh[kp][1], pl.v, acc1);
      acc1 = mfma_bf16(vfh[kp][1], ph.v, acc1);
      __builtin_amdgcn_s_setprio(0);
    }
    // rotate prefetched K into current
#pragma unroll
    for (int ds = 0; ds < 4; ++ds) { kah[ds] = knh[ds]; kal[ds] = knl[ds]; }
  }

  // write seg partials: O^T [64 d][32 q] + l,m per q
  float* o = segO + (size_t)bid * 2048;
#pragma unroll
  for (int md = 0; md < 2; ++md) {
#pragma unroll
    for (int r2 = 0; r2 < 16; ++r2) {
      int d = md * 32 + (r2 & 3) + 8 * (r2 >> 2) + 4 * h;
      float val = md ? acc1[r2] : acc0[r2];
      o[d * 32 + l31] = val;
    }
  }
  if (h == 0) {
    segL[(size_t)bid * 32 + l31] = lrun;
    segM[(size_t)bid * 32 + l31] = Mrun;
  }
}

// ---------- combine: merge <=8 segs per (b, qt), normalize, transpose, write ----------
__global__ __launch_bounds__(256) void combine_kernel(
    const float* __restrict__ segO, const float* __restrict__ segL,
    const float* __restrict__ segM, float* __restrict__ out)
{
  __shared__ float Sc[8][32];
  __shared__ float Linv[32];
  __shared__ float Ot[64 * 40];

  const int bq = blockIdx.x;            // 0..511
  const int b = bq >> 6, qt = bq & 63;
  const int g = qt >> 3, nsg = g + 1;
  const int base = 4 * g * (g + 1) + (qt & 7) * nsg;   // r of seg 0
  const int tid = threadIdx.x;

  if (tid < 32) {
    float M = -3e38f;
    for (int s = 0; s < nsg; ++s)
      M = fmaxf(M, segM[(size_t)((base + s) * 8 + b) * 32 + tid]);
    float L = 0.f;
    for (int s = 0; s < nsg; ++s) {
      float e = __expf(segM[(size_t)((base + s) * 8 + b) * 32 + tid] - M);
      Sc[s][tid] = e;
      L += e * segL[(size_t)((base + s) * 8 + b) * 32 + tid];
    }
    Linv[tid] = 1.f / L;
  }
  __syncthreads();
  {
#pragma unroll
    for (int i = tid; i < 512; i += 256) {
      int d = i >> 3, q4 = (i & 7) * 4;
      float4 acc = {0.f, 0.f, 0.f, 0.f};
      for (int s = 0; s < nsg; ++s) {
        float4 v = *(const float4*)(segO + (size_t)((base + s) * 8 + b) * 2048 + d * 32 + q4);
        acc.x += Sc[s][q4 + 0] * v.x;
        acc.y += Sc[s][q4 + 1] * v.y;
        acc.z += Sc[s][q4 + 2] * v.z;
        acc.w += Sc[s][q4 + 3] * v.w;
      }
      *(float4*)&Ot[d * 40 + q4] = acc;
    }
  }
  __syncthreads();
  {
    const int q = tid >> 3, dc = (tid & 7) * 8;
    const float inv = Linv[q];
    float* dst = out + ((size_t)b * 2048 + qt * 32 + q) * 64 + dc;
#pragma unroll
    for (int i = 0; i < 2; ++i) {
      float4 o;
      o.x = Ot[(dc + 4 * i + 0) * 40 + q] * inv;
      o.y = Ot[(dc + 4 * i + 1) * 40 + q] * inv;
      o.z = Ot[(dc + 4 * i + 2) * 40 + q] * inv;
      o.w = Ot[(dc + 4 * i + 3) * 40 + q] * inv;
      *(float4*)(dst + 4 * i) = o;
    }
  }
}

// ---------- launch ----------
extern "C" void kernel_launch(void* const* d_in, const int* in_sizes, int n_in,
                              void* d_out, int out_size, void* d_ws, size_t ws_size,
                              hipStream_t stream) {
  const float* x  = (const float*)d_in[0];
  const float* Wq = (const float*)d_in[1];
  const float* Wk = (const float*)d_in[2];
  const float* Wv = (const float*)d_in[3];

  char* wsb = (char*)d_ws;
  short* wsB = (short*)(wsb + 0);                     // 786432 B
  short* qh  = (short*)(wsb + 786432);
  short* ql  = (short*)(wsb + 2883584);
  short* kh  = (short*)(wsb + 4980736);
  short* kl  = (short*)(wsb + 7077888);
  short* vth = (short*)(wsb + 9175040);
  short* vtl = (short*)(wsb + 11272192);
  float* segO = (float*)(wsb + 13369344);             // 2304*2048*4 = 18874368 B
  float* segL = (float*)(wsb + 32243712);             // 294912 B
  float* segM = (float*)(wsb + 32538624);             // 294912 B

  wconv_kernel<<<192, 256, 0, stream>>>(Wq, Wk, Wv, wsB);
  proj_kernel<<<512, 256, 0, stream>>>(x, wsB, qh, ql, kh, kl, vth, vtl);
  attn_kernel<<<2304, 64, 0, stream>>>(qh, ql, kh, kl, vth, vtl, segO, segL, segM);
  combine_kernel<<<512, 256, 0, stream>>>(segO, segL, segM, (float*)d_out);
}